// Round 10
// baseline (911.276 us; speedup 1.0000x reference)
//
#include <hip/hip_runtime.h>
#include <hip/hip_bf16.h>

#define NTOK 4096
#define DM   2048
#define DF   4096
#define NEXP 8
#define NPAD 10240   // max padded rows: 8192 + 8*255, rounded up
#define NPTILE 40    // NPAD / 256

typedef __attribute__((ext_vector_type(4))) float f32x4;
typedef __attribute__((ext_vector_type(8))) short s16x8;
typedef __attribute__((ext_vector_type(2))) int   i32x2;

__device__ __forceinline__ unsigned short f2bf(float f) {
  union { float f; unsigned u; } x; x.f = f;
  unsigned r = x.u + 0x7fffu + ((x.u >> 16) & 1u);   // RNE to bf16
  return (unsigned short)(r >> 16);
}
__device__ __forceinline__ unsigned pack2(float lo, float hi) {
  __hip_bfloat162 h2 = __float22bfloat162_rn(make_float2(lo, hi));
  return *reinterpret_cast<unsigned*>(&h2);
}
// element (short) offset into a [rows][32] bf16 tile image, 16B-chunk XOR swizzle
__device__ __forceinline__ int swz(int row, int ks) {
  return row * 32 + ((ks ^ ((row >> 1) & 3)) << 3);
}
__device__ __forceinline__ void g2l16(const void* g, void* l) {
  __builtin_amdgcn_global_load_lds(
      (const __attribute__((address_space(1))) void*)g,
      (__attribute__((address_space(3))) void*)l, 16, 0, 0);
}

#define BARRIER() asm volatile("s_barrier" ::: "memory")
#define WAITV(n)  asm volatile("s_waitcnt vmcnt(" #n ")" ::: "memory")

// ---------------- init / routing ----------------
__global__ void k_zero_out(float* out) {
  int gid = blockIdx.x * 256 + threadIdx.x;
  *(f32x4*)(out + (size_t)gid * 4) = f32x4{0.f, 0.f, 0.f, 0.f};
}

__global__ void k_init(int* tokrow, int* counts, int* cursor) {
  int i = blockIdx.x * 256 + threadIdx.x;
  if (i < NPAD) tokrow[i] = 0;
  if (i < NEXP) { counts[i] = 0; cursor[i] = 0; }
}

__global__ void k_count(const int* __restrict__ idx, int* counts) {
  int t = blockIdx.x * 256 + threadIdx.x;
  if (t >= NTOK) return;
  int e0 = idx[2 * t], e1 = idx[2 * t + 1];
  atomicAdd(&counts[e0], 1);
  if (e1 != e0) atomicAdd(&counts[e1], 1);
}

__global__ void k_scan(const int* __restrict__ counts, int* poff) {
  if (threadIdx.x == 0) {
    int s = 0;
    for (int e = 0; e < NEXP; e++) {
      poff[e] = s;
      s += ((counts[e] + 255) & ~255);
    }
  }
}

__global__ void k_fill(const int* __restrict__ idx, const float* __restrict__ wts,
                       const int* __restrict__ poff, int* cursor,
                       int* tokrow, float* wrow) {
  int t = blockIdx.x * 256 + threadIdx.x;
  if (t >= NTOK) return;
  int e0 = idx[2 * t], e1 = idx[2 * t + 1];
  float w0 = wts[2 * t], w1 = wts[2 * t + 1];
  if (e0 == e1) {
    int g = poff[e0] + atomicAdd(&cursor[e0], 1);
    tokrow[g] = t; wrow[g] = w0 + w1;
  } else {
    int g0 = poff[e0] + atomicAdd(&cursor[e0], 1);
    tokrow[g0] = t; wrow[g0] = w0;
    int g1 = poff[e1] + atomicAdd(&cursor[e1], 1);
    tokrow[g1] = t; wrow[g1] = w1;
  }
}

// ---------------- X -> gathered bf16 swizzled tile images ----------------
// Xg layout: [tile (0..39)][kt (0..63)][256x32 image (8192 shorts)]
__global__ void k_convX(const float* __restrict__ X, const int* __restrict__ tokrow,
                        short* __restrict__ Xg) {
  const int kt = blockIdx.x, tile = blockIdx.y, tid = threadIdx.x;
  const int part = tid & 7;
  short* dst = Xg + (size_t)(tile * 64 + kt) * 8192;
  #pragma unroll
  for (int it = 0; it < 8; it++) {
    int row = it * 32 + (tid >> 3);
    int tok = tokrow[tile * 256 + row];
    f32x4 v = *(const f32x4*)(X + (size_t)tok * DM + kt * 32 + part * 4);
    i32x2 p;
    p[0] = (int)pack2(v[0], v[1]);
    p[1] = (int)pack2(v[2], v[3]);
    int idx = row * 32 + (((part >> 1) ^ ((row >> 1) & 3)) << 3) + (part & 1) * 4;
    *(i32x2*)&dst[idx] = p;
  }
}

// ---------------- W (f32 [K][N]) -> bf16 transposed swizzled tile images ----
// dst layout: [e][nt (N/128)][kt (K/32)][128x32 image (4096 shorts)]
__global__ void k_convW(const float* __restrict__ W, short* __restrict__ dst,
                        int N, int K) {
  const int nt = blockIdx.x, kt = blockIdx.y, e = blockIdx.z;
  const int t = threadIdx.x;
  const int kg = t >> 5, nb = t & 31;           // 4 k-rows, 4 n-cols per thread
  const float* src = W + (size_t)e * K * N + (size_t)(kt * 32 + kg * 4) * N
                     + nt * 128 + nb * 4;
  f32x4 b0 = *(const f32x4*)(src);
  f32x4 b1 = *(const f32x4*)(src + N);
  f32x4 b2 = *(const f32x4*)(src + 2 * (size_t)N);
  f32x4 b3 = *(const f32x4*)(src + 3 * (size_t)N);
  short* img = dst + ((size_t)(e * (N / 128) + nt) * (K / 32) + kt) * 4096;
  const int c0 = kg >> 1, klo = (kg & 1) * 4;   // k-chunk, offset within chunk
  #pragma unroll
  for (int j = 0; j < 4; j++) {
    int nl = nb * 4 + j;
    i32x2 v;
    v[0] = (int)pack2(b0[j], b1[j]);
    v[1] = (int)pack2(b2[j], b3[j]);
    *(i32x2*)&img[nl * 32 + ((c0 ^ ((nl >> 1) & 3)) << 3) + klo] = v;
  }
}

// ---------------- GEMM1: Hs = swiglu(Xg x Wgt, Xg x Wut) --------------------
// A ring mod-3 (ready at use), B ring mod-5 (ready 1 step early -> register
// prefetch of B frags overlaps LDS reads with MFMA). Counted-vmcnt ledger:
// prologue vmcnt(2); kt=0 ->4; steady ->6; tail 4/2/0. XCD chunk swizzle.
__global__ __launch_bounds__(512, 2) void gemm1_kernel(
    const short* __restrict__ Xg, const short* __restrict__ Wgt,
    const short* __restrict__ Wut, const int* __restrict__ counts,
    const int* __restrict__ poff, unsigned short* __restrict__ Hs) {
  const int e = blockIdx.z;
  // XCD chunk swizzle: consecutive-dispatch blocks round-robin XCDs; give each
  // XCD a contiguous 64-block chunk (4 nt-groups x 16 y) for B L2 residency.
  const int lid = blockIdx.x;                       // 0..511
  const int logical = ((lid & 7) << 6) | (lid >> 3);
  const int nt = logical >> 4;                      // 0..31
  const int yt = logical & 15;                      // 0..15
  const int cnt = counts[e];
  const int m0 = yt * 256;
  if (m0 >= cnt) return;
  const int n0 = nt * 128;
  const int tileIdx = (poff[e] >> 8) + yt;

  __shared__ __attribute__((aligned(16))) short As[3][8192];     // 48 KiB
  __shared__ __attribute__((aligned(16))) short Bs[5][2][4096];  // 80 KiB

  const int tid = threadIdx.x, wave = tid >> 6, lane = tid & 63;
  const int wm = wave >> 1, wn = wave & 1;
  const int lr = lane & 15, ks = lane >> 4;

  const short* aSrc = Xg + (size_t)tileIdx * 64 * 8192 + wave * 1024 + lane * 8;
  const short* gSrc = Wgt + (size_t)(e * 32 + nt) * 64 * 4096 + wave * 512 + lane * 8;
  const short* uSrc = Wut + (size_t)(e * 32 + nt) * 64 * 4096 + wave * 512 + lane * 8;

  f32x4 accg[4][4], accu[4][4];
  #pragma unroll
  for (int i = 0; i < 4; i++)
    #pragma unroll
    for (int j = 0; j < 4; j++) {
      accg[i][j] = f32x4{0.f, 0.f, 0.f, 0.f};
      accu[i][j] = f32x4{0.f, 0.f, 0.f, 0.f};
    }

  auto stageA = [&](int s, int kt) {   // 2 vmem loads per thread
    g2l16(aSrc + (size_t)kt * 8192,       &As[s][wave * 1024]);
    g2l16(aSrc + (size_t)kt * 8192 + 512, &As[s][wave * 1024 + 512]);
  };
  auto stageB = [&](int s, int kt) {   // 2 vmem loads per thread
    g2l16(gSrc + (size_t)kt * 4096, &Bs[s][0][wave * 512]);
    g2l16(uSrc + (size_t)kt * 4096, &Bs[s][1][wave * 512]);
  };

  const int nK = DM / 32;   // 64
  // prologue: B0,B1,B2,B3,A0,A1 issued in this exact order (FIFO ledger)
  stageB(0, 0); stageB(1, 1); stageB(2, 2); stageB(3, 3);
  stageA(0, 0); stageA(1, 1);
  WAITV(2);                 // retires B0..B3, A0 (A1 outstanding)
  BARRIER();

  s16x8 bgX[4], buX[4], bgY[4], buY[4];
  #pragma unroll
  for (int ni = 0; ni < 4; ni++) {        // prefetch B frags for kt=0
    bgX[ni] = *(const s16x8*)&Bs[0][0][swz(wn * 64 + ni * 16 + lr, ks)];
    buX[ni] = *(const s16x8*)&Bs[0][1][swz(wn * 64 + ni * 16 + lr, ks)];
  }

#define G1STEP(KT, BGC, BUC, BGN, BUN)                                         \
  {                                                                            \
    const int kt_ = (KT);                                                      \
    if (kt_ + 2 < nK) stageA((kt_ + 2) % 3, kt_ + 2);                          \
    if (kt_ + 4 < nK) stageB((kt_ + 4) % 5, kt_ + 4);                          \
    const int sa_ = kt_ % 3;                                                   \
    s16x8 af[4];                                                               \
    _Pragma("unroll")                                                          \
    for (int mi = 0; mi < 4; mi++)                                             \
      af[mi] = *(const s16x8*)&As[sa_][swz(wm * 64 + mi * 16 + lr, ks)];       \
    if (kt_ + 1 < nK) {                                                        \
      const int sb_ = (kt_ + 1) % 5;                                           \
      _Pragma("unroll")                                                        \
      for (int ni = 0; ni < 4; ni++) {                                         \
        BGN[ni] = *(const s16x8*)&Bs[sb_][0][swz(wn * 64 + ni * 16 + lr, ks)]; \
        BUN[ni] = *(const s16x8*)&Bs[sb_][1][swz(wn * 64 + ni * 16 + lr, ks)]; \
      }                                                                        \
    }                                                                          \
    __builtin_amdgcn_s_setprio(1);                                             \
    _Pragma("unroll")                                                          \
    for (int mi = 0; mi < 4; mi++)                                             \
      _Pragma("unroll")                                                        \
      for (int ni = 0; ni < 4; ni++) {                                         \
        accg[mi][ni] = __builtin_amdgcn_mfma_f32_16x16x32_bf16(                \
            af[mi], BGC[ni], accg[mi][ni], 0, 0, 0);                           \
        accu[mi][ni] = __builtin_amdgcn_mfma_f32_16x16x32_bf16(                \
            af[mi], BUC[ni], accu[mi][ni], 0, 0, 0);                           \
      }                                                                        \
    __builtin_amdgcn_s_setprio(0);                                             \
    if (kt_ == 0)           { WAITV(4); BARRIER(); }                           \
    else if (kt_ <= nK - 5) { WAITV(6); BARRIER(); }                           \
    else if (kt_ == nK - 4) { WAITV(4); BARRIER(); }                           \
    else if (kt_ == nK - 3) { WAITV(2); BARRIER(); }                           \
    else if (kt_ == nK - 2) { WAITV(0); BARRIER(); }                           \
  }

  for (int kt = 0; kt < nK; kt += 2) {
    G1STEP(kt,     bgX, buX, bgY, buY)
    G1STEP(kt + 1, bgY, buY, bgX, buX)
  }
#undef G1STEP

  // epilogue: silu(g)*u -> Hs in gemm2's swizzled tile-image layout
  const size_t tb = (size_t)tileIdx * 128 * 8192;
  #pragma unroll
  for (int mi = 0; mi < 4; mi++) {
    #pragma unroll
    for (int r = 0; r < 4; r++) {
      int row = wm * 64 + mi * 16 + ks * 4 + r;
      if (m0 + row < cnt) {
        #pragma unroll
        for (int ni = 0; ni < 4; ni++) {
          int col = n0 + wn * 64 + ni * 16 + lr;
          float g = accg[mi][ni][r], u = accu[mi][ni][r];
          float sv = g / (1.f + __expf(-g));
          int ktH = col >> 5, kl = col & 31;
          Hs[tb + (size_t)ktH * 8192 + row * 32 +
             (((kl >> 3) ^ ((row >> 1) & 3)) << 3) + (kl & 7)] = f2bf(sv * u);
        }
      }
    }
  }
}

// ---------------- GEMM2: out += (Hs x Wdt) * w_row, 128x256 dual-B ----------
// (round-9 proven verbatim)
__global__ __launch_bounds__(256, 2) void gemm2_kernel(
    const unsigned short* __restrict__ Hs, const short* __restrict__ Wdt,
    const int* __restrict__ counts, const int* __restrict__ poff,
    const int* __restrict__ tokrow, const float* __restrict__ wrow,
    float* __restrict__ out) {
  const int e = blockIdx.z;
  const int cnt = counts[e];
  const int m0 = blockIdx.y * 128;
  if (m0 >= cnt) return;
  const int nt = blockIdx.x, n0 = nt * 256;
  const int tileIdx = (poff[e] >> 8) + (m0 >> 8);
  const int half = (m0 >> 7) & 1;

  __shared__ __attribute__((aligned(16))) short As[2][4096];     // 16 KiB
  __shared__ __attribute__((aligned(16))) short Bs[2][2][4096];  // 32 KiB
  __shared__ float wl[128];
  __shared__ int   tl[128];

  const int tid = threadIdx.x, wave = tid >> 6, lane = tid & 63;
  const int wm = wave >> 1, wn = wave & 1;
  const int lr = lane & 15, ks = lane >> 4;

  if (tid < 128) {
    int rp = poff[e] + m0 + tid;
    wl[tid] = wrow[rp];
    tl[tid] = tokrow[rp];
  }

  const unsigned short* aSrc = Hs + (size_t)tileIdx * 128 * 8192 + half * 4096
                               + wave * 1024 + lane * 8;
  const short* b0Src = Wdt + (size_t)(e * 16 + 2 * nt) * 128 * 4096
                       + wave * 1024 + lane * 8;
  const short* b1Src = Wdt + (size_t)(e * 16 + 2 * nt + 1) * 128 * 4096
                       + wave * 1024 + lane * 8;

  f32x4 acc0[4][4], acc1[4][4];
  #pragma unroll
  for (int i = 0; i < 4; i++)
    #pragma unroll
    for (int j = 0; j < 4; j++) {
      acc0[i][j] = f32x4{0.f, 0.f, 0.f, 0.f};
      acc1[i][j] = f32x4{0.f, 0.f, 0.f, 0.f};
    }

  auto stage = [&](int b, int kt) {   // 6 vmem ops per thread
    g2l16(aSrc + (size_t)kt * 8192,        &As[b][wave * 1024]);
    g2l16(aSrc + (size_t)kt * 8192 + 512,  &As[b][wave * 1024 + 512]);
    g2l16(b0Src + (size_t)kt * 4096,       &Bs[b][0][wave * 1024]);
    g2l16(b0Src + (size_t)kt * 4096 + 512, &Bs[b][0][wave * 1024 + 512]);
    g2l16(b1Src + (size_t)kt * 4096,       &Bs[b][1][wave * 1024]);
    g2l16(b1Src + (size_t)kt * 4096 + 512, &Bs[b][1][wave * 1024 + 512]);
  };

  stage(0, 0);
  __syncthreads();
  int buf = 0;
  const int nK = DF / 32;
  for (int kt = 0; kt < nK; ++kt) {
    if (kt + 1 < nK) stage(buf ^ 1, kt + 1);
    s16x8 af[4], b0f[4], b1f[4];
    #pragma unroll
    for (int mi = 0; mi < 4; mi++)
      af[mi] = *(const s16x8*)&As[buf][swz(wm * 64 + mi * 16 + lr, ks)];
    #pragma unroll
    for (int ni = 0; ni < 4; ni++) {
      b0f[ni] = *(const s16x8*)&Bs[buf][0][swz(wn * 64 + ni * 16 + lr, ks)];
      b1f[ni] = *(const s16x8*)&Bs[buf][1][swz(wn * 64 + ni * 16 + lr, ks)];
    }
    __builtin_amdgcn_s_setprio(1);
    #pragma unroll
    for (int mi = 0; mi < 4; mi++)
      #pragma unroll
      for (int ni = 0; ni < 4; ni++) {
        acc0[mi][ni] = __builtin_amdgcn_mfma_f32_16x16x32_bf16(af[mi], b0f[ni], acc0[mi][ni], 0, 0, 0);
        acc1[mi][ni] = __builtin_amdgcn_mfma_f32_16x16x32_bf16(af[mi], b1f[ni], acc1[mi][ni], 0, 0, 0);
      }
    __builtin_amdgcn_s_setprio(0);
    __syncthreads();
    buf ^= 1;
  }

  #pragma unroll
  for (int mi = 0; mi < 4; mi++) {
    #pragma unroll
    for (int r = 0; r < 4; r++) {
      int lrow = wm * 64 + mi * 16 + ks * 4 + r;
      if (m0 + lrow < cnt) {
        float wgt = wl[lrow];
        float* obase = out + (size_t)tl[lrow] * DM + n0 + wn * 64 + lr;
        #pragma unroll
        for (int ni = 0; ni < 4; ni++) {
          atomicAdd(obase + ni * 16,       acc0[mi][ni][r] * wgt);
          atomicAdd(obase + 128 + ni * 16, acc1[mi][ni][r] * wgt);
        }
      }
    }
  }
}

extern "C" void kernel_launch(void* const* d_in, const int* in_sizes, int n_in,
                              void* d_out, int out_size, void* d_ws, size_t ws_size,
                              hipStream_t stream) {
  (void)in_sizes; (void)n_in; (void)out_size; (void)ws_size;
  const float* X   = (const float*)d_in[0];
  const int*   idx = (const int*)d_in[1];
  const float* wts = (const float*)d_in[2];
  const float* Wg  = (const float*)d_in[3];
  const float* Wu  = (const float*)d_in[4];
  const float* Wd  = (const float*)d_in[5];
  float* out = (float*)d_out;

  uint8_t* w = (uint8_t*)d_ws;
  int*   counts = (int*)(w + 0);
  int*   cursor = (int*)(w + 64);
  int*   poff   = (int*)(w + 128);
  int*   tokrow = (int*)(w + 4096);
  float* wrow   = (float*)(w + 49152);
  short* Xg     = (short*)(w + (1ull << 20));                  // 40 MiB
  unsigned short* Hs = (unsigned short*)(w + (48ull << 20));   // 80 MiB
  short* Wgt    = (short*)(w + (128ull << 20));                // 128 MiB
  short* Wut    = (short*)(w + (256ull << 20));                // 128 MiB
  short* Wdt    = (short*)(w + (384ull << 20));                // 128 MiB

  k_zero_out<<<NTOK * DM / 1024, 256, 0, stream>>>(out);
  k_init<<<NPTILE, 256, 0, stream>>>(tokrow, counts, cursor);
  k_count<<<16, 256, 0, stream>>>(idx, counts);
  k_scan<<<1, 64, 0, stream>>>(counts, poff);
  k_fill<<<16, 256, 0, stream>>>(idx, wts, poff, cursor, tokrow, wrow);
  k_convX<<<dim3(DM / 32, NPTILE), 256, 0, stream>>>(X, tokrow, Xg);
  k_convW<<<dim3(DF / 128, DM / 32, NEXP), 256, 0, stream>>>(Wg, Wgt, DF, DM);
  k_convW<<<dim3(DF / 128, DM / 32, NEXP), 256, 0, stream>>>(Wu, Wut, DF, DM);
  k_convW<<<dim3(DM / 128, DF / 32, NEXP), 256, 0, stream>>>(Wd, Wdt, DM, DF);
  gemm1_kernel<<<dim3(512, 1, NEXP), 512, 0, stream>>>(Xg, Wgt, Wut, counts, poff, Hs);
  gemm2_kernel<<<dim3(DM / 256, 32, NEXP), 256, 0, stream>>>(Hs, Wdt, counts, poff, tokrow, wrow, out);
}

// Round 11
// 885.900 us; speedup vs baseline: 1.0286x; 1.0286x over previous
//
#include <hip/hip_runtime.h>
#include <hip/hip_bf16.h>

#define NTOK 4096
#define DM   2048
#define DF   4096
#define NEXP 8
#define NPAD 10240   // max padded rows: 8192 + 8*255, rounded up
#define NPTILE 40    // NPAD / 256

typedef __attribute__((ext_vector_type(4))) float f32x4;
typedef __attribute__((ext_vector_type(8))) short s16x8;
typedef __attribute__((ext_vector_type(2))) int   i32x2;

__device__ __forceinline__ unsigned short f2bf(float f) {
  union { float f; unsigned u; } x; x.f = f;
  unsigned r = x.u + 0x7fffu + ((x.u >> 16) & 1u);   // RNE to bf16
  return (unsigned short)(r >> 16);
}
__device__ __forceinline__ unsigned pack2(float lo, float hi) {
  __hip_bfloat162 h2 = __float22bfloat162_rn(make_float2(lo, hi));
  return *reinterpret_cast<unsigned*>(&h2);
}
// element (short) offset into a [rows][32] bf16 tile image, 16B-chunk XOR swizzle
__device__ __forceinline__ int swz(int row, int ks) {
  return row * 32 + ((ks ^ ((row >> 1) & 3)) << 3);
}
__device__ __forceinline__ void g2l16(const void* g, void* l) {
  __builtin_amdgcn_global_load_lds(
      (const __attribute__((address_space(1))) void*)g,
      (__attribute__((address_space(3))) void*)l, 16, 0, 0);
}

#define BARRIER() asm volatile("s_barrier" ::: "memory")
#define WAITV(n)  asm volatile("s_waitcnt vmcnt(" #n ")" ::: "memory")

// ---------------- init / routing ----------------
__global__ void k_zero_out(float* out) {
  int gid = blockIdx.x * 256 + threadIdx.x;
  *(f32x4*)(out + (size_t)gid * 4) = f32x4{0.f, 0.f, 0.f, 0.f};
}

__global__ void k_init(int* tokrow, int* counts, int* cursor) {
  int i = blockIdx.x * 256 + threadIdx.x;
  if (i < NPAD) tokrow[i] = 0;
  if (i < NEXP) { counts[i] = 0; cursor[i] = 0; }
}

__global__ void k_count(const int* __restrict__ idx, int* counts) {
  int t = blockIdx.x * 256 + threadIdx.x;
  if (t >= NTOK) return;
  int e0 = idx[2 * t], e1 = idx[2 * t + 1];
  atomicAdd(&counts[e0], 1);
  if (e1 != e0) atomicAdd(&counts[e1], 1);
}

__global__ void k_scan(const int* __restrict__ counts, int* poff) {
  if (threadIdx.x == 0) {
    int s = 0;
    for (int e = 0; e < NEXP; e++) {
      poff[e] = s;
      s += ((counts[e] + 255) & ~255);
    }
  }
}

__global__ void k_fill(const int* __restrict__ idx, const float* __restrict__ wts,
                       const int* __restrict__ poff, int* cursor,
                       int* tokrow, float* wrow) {
  int t = blockIdx.x * 256 + threadIdx.x;
  if (t >= NTOK) return;
  int e0 = idx[2 * t], e1 = idx[2 * t + 1];
  float w0 = wts[2 * t], w1 = wts[2 * t + 1];
  if (e0 == e1) {
    int g = poff[e0] + atomicAdd(&cursor[e0], 1);
    tokrow[g] = t; wrow[g] = w0 + w1;
  } else {
    int g0 = poff[e0] + atomicAdd(&cursor[e0], 1);
    tokrow[g0] = t; wrow[g0] = w0;
    int g1 = poff[e1] + atomicAdd(&cursor[e1], 1);
    tokrow[g1] = t; wrow[g1] = w1;
  }
}

// ---------------- X -> gathered bf16 swizzled tile images ----------------
// Xg layout: [tile (0..39)][kt (0..63)][256x32 image (8192 shorts)]
__global__ void k_convX(const float* __restrict__ X, const int* __restrict__ tokrow,
                        short* __restrict__ Xg) {
  const int kt = blockIdx.x, tile = blockIdx.y, tid = threadIdx.x;
  const int part = tid & 7;
  short* dst = Xg + (size_t)(tile * 64 + kt) * 8192;
  #pragma unroll
  for (int it = 0; it < 8; it++) {
    int row = it * 32 + (tid >> 3);
    int tok = tokrow[tile * 256 + row];
    f32x4 v = *(const f32x4*)(X + (size_t)tok * DM + kt * 32 + part * 4);
    i32x2 p;
    p[0] = (int)pack2(v[0], v[1]);
    p[1] = (int)pack2(v[2], v[3]);
    int idx = row * 32 + (((part >> 1) ^ ((row >> 1) & 3)) << 3) + (part & 1) * 4;
    *(i32x2*)&dst[idx] = p;
  }
}

// ---------------- W (f32 [K][N]) -> bf16 transposed swizzled tile images ----
// dst layout: [e][nt (N/128)][kt (K/32)][128x32 image (4096 shorts)]
__global__ void k_convW(const float* __restrict__ W, short* __restrict__ dst,
                        int N, int K) {
  const int nt = blockIdx.x, kt = blockIdx.y, e = blockIdx.z;
  const int t = threadIdx.x;
  const int kg = t >> 5, nb = t & 31;           // 4 k-rows, 4 n-cols per thread
  const float* src = W + (size_t)e * K * N + (size_t)(kt * 32 + kg * 4) * N
                     + nt * 128 + nb * 4;
  f32x4 b0 = *(const f32x4*)(src);
  f32x4 b1 = *(const f32x4*)(src + N);
  f32x4 b2 = *(const f32x4*)(src + 2 * (size_t)N);
  f32x4 b3 = *(const f32x4*)(src + 3 * (size_t)N);
  short* img = dst + ((size_t)(e * (N / 128) + nt) * (K / 32) + kt) * 4096;
  const int c0 = kg >> 1, klo = (kg & 1) * 4;   // k-chunk, offset within chunk
  #pragma unroll
  for (int j = 0; j < 4; j++) {
    int nl = nb * 4 + j;
    i32x2 v;
    v[0] = (int)pack2(b0[j], b1[j]);
    v[1] = (int)pack2(b2[j], b3[j]);
    *(i32x2*)&img[nl * 32 + ((c0 ^ ((nl >> 1) & 3)) << 3) + klo] = v;
  }
}

// ---------------- GEMM1: Hs = swiglu(Xg x Wgt, Xg x Wut) --------------------
// Depth-3 counted-vmcnt pipeline over 4 LDS slots (round-7 proven, 397 us).
__global__ __launch_bounds__(512, 2) void gemm1_kernel(
    const short* __restrict__ Xg, const short* __restrict__ Wgt,
    const short* __restrict__ Wut, const int* __restrict__ counts,
    const int* __restrict__ poff, unsigned short* __restrict__ Hs) {
  const int e = blockIdx.z;
  const int cnt = counts[e];
  const int m0 = blockIdx.y * 256;
  if (m0 >= cnt) return;
  const int nt = blockIdx.x, n0 = nt * 128;
  const int tileIdx = (poff[e] >> 8) + blockIdx.y;

  __shared__ __attribute__((aligned(16))) short As[4][8192];     // 64 KiB
  __shared__ __attribute__((aligned(16))) short Bs[4][2][4096];  // 64 KiB

  const int tid = threadIdx.x, wave = tid >> 6, lane = tid & 63;
  const int wm = wave >> 1, wn = wave & 1;
  const int lr = lane & 15, ks = lane >> 4;

  const short* aSrc = Xg + (size_t)tileIdx * 64 * 8192 + wave * 1024 + lane * 8;
  const short* gSrc = Wgt + (size_t)(e * 32 + nt) * 64 * 4096 + wave * 512 + lane * 8;
  const short* uSrc = Wut + (size_t)(e * 32 + nt) * 64 * 4096 + wave * 512 + lane * 8;

  f32x4 accg[4][4], accu[4][4];
  #pragma unroll
  for (int i = 0; i < 4; i++)
    #pragma unroll
    for (int j = 0; j < 4; j++) {
      accg[i][j] = f32x4{0.f, 0.f, 0.f, 0.f};
      accu[i][j] = f32x4{0.f, 0.f, 0.f, 0.f};
    }

  auto stage = [&](int s, int kt) {   // 4 vmem ops per thread
    g2l16(aSrc + (size_t)kt * 8192,       &As[s][wave * 1024]);
    g2l16(aSrc + (size_t)kt * 8192 + 512, &As[s][wave * 1024 + 512]);
    g2l16(gSrc + (size_t)kt * 4096,       &Bs[s][0][wave * 512]);
    g2l16(uSrc + (size_t)kt * 4096,       &Bs[s][1][wave * 512]);
  };

  const int nK = DM / 32;
  stage(0, 0); stage(1, 1); stage(2, 2);          // 12 in flight
  asm volatile("s_waitcnt vmcnt(8) lgkmcnt(0)" ::: "memory");  // slot0 ready
  BARRIER();

  for (int kt = 0; kt < nK; ++kt) {
    const int s = kt & 3;
    if (kt + 3 < nK) stage((kt + 3) & 3, kt + 3); // issue-early prefetch
    s16x8 af[4], bg[4], bu[4];
    #pragma unroll
    for (int mi = 0; mi < 4; mi++)
      af[mi] = *(const s16x8*)&As[s][swz(wm * 64 + mi * 16 + lr, ks)];
    #pragma unroll
    for (int ni = 0; ni < 4; ni++) {
      bg[ni] = *(const s16x8*)&Bs[s][0][swz(wn * 64 + ni * 16 + lr, ks)];
      bu[ni] = *(const s16x8*)&Bs[s][1][swz(wn * 64 + ni * 16 + lr, ks)];
    }
    __builtin_amdgcn_s_setprio(1);
    #pragma unroll
    for (int mi = 0; mi < 4; mi++)
      #pragma unroll
      for (int ni = 0; ni < 4; ni++) {
        accg[mi][ni] = __builtin_amdgcn_mfma_f32_16x16x32_bf16(af[mi], bg[ni], accg[mi][ni], 0, 0, 0);
        accu[mi][ni] = __builtin_amdgcn_mfma_f32_16x16x32_bf16(af[mi], bu[ni], accu[mi][ni], 0, 0, 0);
      }
    __builtin_amdgcn_s_setprio(0);
    if (kt + 1 < nK) {
      if (kt + 3 < nK)      { WAITV(8); }         // retire slot kt+1's loads
      else if (kt + 2 < nK) { WAITV(4); }
      else                  { WAITV(0); }
      BARRIER();
    }
  }

  // epilogue: silu(g)*u -> Hs in gemm2's swizzled tile-image layout
  const size_t tb = (size_t)tileIdx * 128 * 8192;
  #pragma unroll
  for (int mi = 0; mi < 4; mi++) {
    #pragma unroll
    for (int r = 0; r < 4; r++) {
      int row = wm * 64 + mi * 16 + ks * 4 + r;
      if (m0 + row < cnt) {
        #pragma unroll
        for (int ni = 0; ni < 4; ni++) {
          int col = n0 + wn * 64 + ni * 16 + lr;
          float g = accg[mi][ni][r], u = accu[mi][ni][r];
          float sv = g / (1.f + __expf(-g));
          int ktH = col >> 5, kl = col & 31;
          Hs[tb + (size_t)ktH * 8192 + row * 32 +
             (((kl >> 3) ^ ((row >> 1) & 3)) << 3) + (kl & 7)] = f2bf(sv * u);
        }
      }
    }
  }
}

// ---------------- GEMM2: out += (Hs x Wdt) * w_row, 128x256 dual-B ----------
// Depth-2 counted-vmcnt ring over 3 LDS slots (24 KiB each) -> 2 blocks/CU.
// Uniform 6 loads/thread/step; ledger: prologue 12, WAITV(6); steady WAITV(6);
// tail WAITV(0). No extra vector loads before/inside the loop (wrow/tokrow
// read directly in the epilogue to keep the vmcnt FIFO clean).
__global__ __launch_bounds__(256, 2) void gemm2_kernel(
    const unsigned short* __restrict__ Hs, const short* __restrict__ Wdt,
    const int* __restrict__ counts, const int* __restrict__ poff,
    const int* __restrict__ tokrow, const float* __restrict__ wrow,
    float* __restrict__ out) {
  const int e = blockIdx.z;
  const int cnt = counts[e];
  const int m0 = blockIdx.y * 128;
  if (m0 >= cnt) return;
  const int nt = blockIdx.x, n0 = nt * 256;
  const int tileIdx = (poff[e] >> 8) + (m0 >> 8);
  const int half = (m0 >> 7) & 1;
  const int roff = poff[e];

  __shared__ __attribute__((aligned(16))) short As[3][4096];     // 24 KiB
  __shared__ __attribute__((aligned(16))) short Bs[3][2][4096];  // 48 KiB

  const int tid = threadIdx.x, wave = tid >> 6, lane = tid & 63;
  const int wm = wave >> 1, wn = wave & 1;
  const int lr = lane & 15, ks = lane >> 4;

  // A: 128-row half of a 256-row Hs k-image (row-mod-8 periodic layout -> valid)
  const unsigned short* aSrc = Hs + (size_t)tileIdx * 128 * 8192 + half * 4096
                               + wave * 1024 + lane * 8;
  const short* b0Src = Wdt + (size_t)(e * 16 + 2 * nt) * 128 * 4096
                       + wave * 1024 + lane * 8;
  const short* b1Src = Wdt + (size_t)(e * 16 + 2 * nt + 1) * 128 * 4096
                       + wave * 1024 + lane * 8;

  f32x4 acc0[4][4], acc1[4][4];
  #pragma unroll
  for (int i = 0; i < 4; i++)
    #pragma unroll
    for (int j = 0; j < 4; j++) {
      acc0[i][j] = f32x4{0.f, 0.f, 0.f, 0.f};
      acc1[i][j] = f32x4{0.f, 0.f, 0.f, 0.f};
    }

  auto stage = [&](int s, int kt) {   // 6 vmem ops per thread, fixed order
    g2l16(aSrc + (size_t)kt * 8192,        &As[s][wave * 1024]);
    g2l16(aSrc + (size_t)kt * 8192 + 512,  &As[s][wave * 1024 + 512]);
    g2l16(b0Src + (size_t)kt * 4096,       &Bs[s][0][wave * 1024]);
    g2l16(b0Src + (size_t)kt * 4096 + 512, &Bs[s][0][wave * 1024 + 512]);
    g2l16(b1Src + (size_t)kt * 4096,       &Bs[s][1][wave * 1024]);
    g2l16(b1Src + (size_t)kt * 4096 + 512, &Bs[s][1][wave * 1024 + 512]);
  };

  const int nK = DF / 32;   // 128
  stage(0, 0); stage(1, 1);                     // 12 in flight
  WAITV(6);                                     // slot0 ready
  BARRIER();

  for (int kt = 0; kt < nK; ++kt) {
    const int s = kt % 3;
    if (kt + 2 < nK) stage((kt + 2) % 3, kt + 2);   // safe: that slot's readers
                                                    // barrier'd at end of kt-1
    s16x8 af[4], b0f[4], b1f[4];
    #pragma unroll
    for (int mi = 0; mi < 4; mi++)
      af[mi] = *(const s16x8*)&As[s][swz(wm * 64 + mi * 16 + lr, ks)];
    #pragma unroll
    for (int ni = 0; ni < 4; ni++) {
      b0f[ni] = *(const s16x8*)&Bs[s][0][swz(wn * 64 + ni * 16 + lr, ks)];
      b1f[ni] = *(const s16x8*)&Bs[s][1][swz(wn * 64 + ni * 16 + lr, ks)];
    }
    __builtin_amdgcn_s_setprio(1);
    #pragma unroll
    for (int mi = 0; mi < 4; mi++)
      #pragma unroll
      for (int ni = 0; ni < 4; ni++) {
        acc0[mi][ni] = __builtin_amdgcn_mfma_f32_16x16x32_bf16(af[mi], b0f[ni], acc0[mi][ni], 0, 0, 0);
        acc1[mi][ni] = __builtin_amdgcn_mfma_f32_16x16x32_bf16(af[mi], b1f[ni], acc1[mi][ni], 0, 0, 0);
      }
    __builtin_amdgcn_s_setprio(0);
    if (kt + 1 < nK) {
      if (kt + 2 < nK) { WAITV(6); }   // retire slot kt+1's loads
      else             { WAITV(0); }
      BARRIER();
    }
  }

  #pragma unroll
  for (int mi = 0; mi < 4; mi++) {
    #pragma unroll
    for (int r = 0; r < 4; r++) {
      int lrow = wm * 64 + mi * 16 + ks * 4 + r;
      if (m0 + lrow < cnt) {
        float wgt = wrow[roff + m0 + lrow];
        float* obase = out + (size_t)tokrow[roff + m0 + lrow] * DM + n0 + wn * 64 + lr;
        #pragma unroll
        for (int ni = 0; ni < 4; ni++) {
          atomicAdd(obase + ni * 16,       acc0[mi][ni][r] * wgt);
          atomicAdd(obase + 128 + ni * 16, acc1[mi][ni][r] * wgt);
        }
      }
    }
  }
}

extern "C" void kernel_launch(void* const* d_in, const int* in_sizes, int n_in,
                              void* d_out, int out_size, void* d_ws, size_t ws_size,
                              hipStream_t stream) {
  (void)in_sizes; (void)n_in; (void)out_size; (void)ws_size;
  const float* X   = (const float*)d_in[0];
  const int*   idx = (const int*)d_in[1];
  const float* wts = (const float*)d_in[2];
  const float* Wg  = (const float*)d_in[3];
  const float* Wu  = (const float*)d_in[4];
  const float* Wd  = (const float*)d_in[5];
  float* out = (float*)d_out;

  uint8_t* w = (uint8_t*)d_ws;
  int*   counts = (int*)(w + 0);
  int*   cursor = (int*)(w + 64);
  int*   poff   = (int*)(w + 128);
  int*   tokrow = (int*)(w + 4096);
  float* wrow   = (float*)(w + 49152);
  short* Xg     = (short*)(w + (1ull << 20));                  // 40 MiB
  unsigned short* Hs = (unsigned short*)(w + (48ull << 20));   // 80 MiB
  short* Wgt    = (short*)(w + (128ull << 20));                // 128 MiB
  short* Wut    = (short*)(w + (256ull << 20));                // 128 MiB
  short* Wdt    = (short*)(w + (384ull << 20));                // 128 MiB

  k_zero_out<<<NTOK * DM / 1024, 256, 0, stream>>>(out);
  k_init<<<NPTILE, 256, 0, stream>>>(tokrow, counts, cursor);
  k_count<<<16, 256, 0, stream>>>(idx, counts);
  k_scan<<<1, 64, 0, stream>>>(counts, poff);
  k_fill<<<16, 256, 0, stream>>>(idx, wts, poff, cursor, tokrow, wrow);
  k_convX<<<dim3(DM / 32, NPTILE), 256, 0, stream>>>(X, tokrow, Xg);
  k_convW<<<dim3(DF / 128, DM / 32, NEXP), 256, 0, stream>>>(Wg, Wgt, DF, DM);
  k_convW<<<dim3(DF / 128, DM / 32, NEXP), 256, 0, stream>>>(Wu, Wut, DF, DM);
  k_convW<<<dim3(DM / 128, DF / 32, NEXP), 256, 0, stream>>>(Wd, Wdt, DM, DF);
  gemm1_kernel<<<dim3(DF / 128, 16, NEXP), 512, 0, stream>>>(Xg, Wgt, Wut, counts, poff, Hs);
  gemm2_kernel<<<dim3(DM / 256, 32, NEXP), 256, 0, stream>>>(Hs, Wdt, counts, poff, tokrow, wrow, out);
}